// Round 6
// baseline (296.129 us; speedup 1.0000x reference)
//
#include <hip/hip_runtime.h>

typedef __attribute__((ext_vector_type(8))) short short8;
typedef __attribute__((ext_vector_type(4))) float f32x4;

static __device__ __forceinline__ float bf2f(unsigned short u) {
    unsigned int x = ((unsigned int)u) << 16;
    union { unsigned int i; float f; } c; c.i = x; return c.f;
}
static __device__ __forceinline__ unsigned short f2bf(float f) {
    union { float f; unsigned int i; } c; c.f = f;
    unsigned int x = c.i;
    unsigned int r = (x + 0x7FFFu + ((x >> 16) & 1u)) >> 16;
    return (unsigned short)r;
}

// ---------------- prepack W [Cout=128][Cin][7] fp32 -> fragment-linear bf16 ----------------
__global__ void prepack_w(const float* __restrict__ W, unsigned short* __restrict__ Wp,
                          int Cin, int S) {
    int tid = blockIdx.x * blockDim.x + threadIdx.x;
    if (tid >= S * 512) return;
    int lane = tid & 63;
    int f = (tid >> 6) & 7;
    int s = tid >> 9;
    int o = f * 16 + (lane & 15);
    int kbase = s * 32 + 8 * (lane >> 4);
    unsigned short* dst = Wp + (size_t)tid * 8;
#pragma unroll
    for (int j = 0; j < 8; ++j) {
        int kk = kbase + j;
        int t = kk / Cin;
        int c = kk - t * Cin;
        dst[j] = f2bf(W[((size_t)o * Cin + c) * 7 + t]);
    }
}

__global__ void prepack_w_scaled(const float* __restrict__ W, const float2* __restrict__ stats,
                                 unsigned short* __restrict__ Wp, int Cin, int S) {
    int tid = blockIdx.x * blockDim.x + threadIdx.x;
    if (tid >= 2 * S * 512) return;
    int b = tid / (S * 512);
    int rem = tid - b * S * 512;
    int lane = rem & 63;
    int f = (rem >> 6) & 7;
    int s = rem >> 9;
    int o = f * 16 + (lane & 15);
    int kbase = s * 32 + 8 * (lane >> 4);
    unsigned short* dst = Wp + (size_t)tid * 8;
#pragma unroll
    for (int j = 0; j < 8; ++j) {
        int kk = kbase + j;
        int t = kk / Cin;
        int c = kk - t * Cin;
        float scale = stats[b * 128 + c].y;
        dst[j] = f2bf(W[((size_t)o * Cin + c) * 7 + t] * scale);
    }
}

__global__ void fold_bias2(const float* __restrict__ W2, const float* __restrict__ b2,
                           const float2* __restrict__ stats, float* __restrict__ b2out) {
    int b = blockIdx.x, o = threadIdx.x;
    float sum = 0.f;
    for (int c = 0; c < 128; ++c) {
        float2 st = stats[b * 128 + c];
        float sm = st.x * st.y;
        float ws = 0.f;
#pragma unroll
        for (int t = 0; t < 7; ++t) ws += W2[((size_t)o * 128 + c) * 7 + t];
        sum += ws * sm;
    }
    b2out[b * 128 + o] = b2[o] - sum;
}

// ---------------- transpose fp32 [B][C][N] -> bf16 [B][N][ldo] at column offset ----------------
__global__ void transpose_cast(const float* __restrict__ in, unsigned short* __restrict__ out,
                               int C, int N, int ldo, int coff) {
    __shared__ float tile[32][33];
    int b = blockIdx.z;
    int n0 = blockIdx.x * 32;
    int c0 = blockIdx.y * 32;
    const float* inb = in + (size_t)b * C * N;
    unsigned short* outb = out + (size_t)b * N * ldo;
    int tx = threadIdx.x, ty = threadIdx.y;
#pragma unroll
    for (int i = 0; i < 32; i += 8) {
        int c = c0 + ty + i, n = n0 + tx;
        float v = 0.f;
        if (n < N) v = inb[(size_t)c * N + n];
        tile[ty + i][tx] = v;
    }
    __syncthreads();
#pragma unroll
    for (int i = 0; i < 32; i += 8) {
        int n = n0 + ty + i, c = c0 + tx;
        if (n < N) outb[(size_t)n * ldo + coff + c] = f2bf(tile[tx][ty + i]);
    }
}

// ---------------- gather-conv: per-tap LDS staging via global_load_lds ----------------
// Block: 64 points, 4 waves; wave owns 16 points x 128 couts (acc = 8 x f32x4).
// Per tap: stage wave's 16 gathered rows into a private LDS dbuf slice (async,
// per-lane global src pre-XOR-swizzled, linear LDS dst), drain with vmcnt(0)
// once per tap AFTER the previous tap's compute. No s_barrier in the main loop.
template<int CS, int LD, bool STATS>
__global__ __launch_bounds__(256, CS == 128 ? 4 : 2) void conv_lds(
    const unsigned short* __restrict__ src,
    const int* __restrict__ nbrs,
    const unsigned short* __restrict__ Wp, size_t w_bstride8,
    const float* __restrict__ bias, int bias_bstride,
    unsigned short* __restrict__ dst,
    float2* __restrict__ part,
    int N, int coff)
{
    constexpr int ROWB    = CS * 2;        // bytes per row
    constexpr int WAVEBUF = 16 * ROWB;     // one tap buffer per wave (8KB / 4KB)
    constexpr int SPT     = CS / 32;       // K-steps per tap
    constexpr int NI      = WAVEBUF / 1024;// global_load_lds instrs per stage

    const int lane = threadIdx.x & 63;
    const int wid  = threadIdx.x >> 6;
    const int b    = blockIdx.y;
    const int l15  = lane & 15;
    const int ks   = lane >> 4;
    const int pw   = blockIdx.x * 64 + wid * 16;  // wave's first point

    const char* srcb_c = (const char*)(src + (size_t)b * N * CS);
    const short8* wb = reinterpret_cast<const short8*>(Wp) + (size_t)b * w_bstride8;
    const float* biasb = bias + (size_t)b * bias_bstride;

    __shared__ char smem[4 * 2 * WAVEBUF];
    char* wavebase = smem + wid * (2 * WAVEBUF);

    // per-lane row byte-offsets for the wave's 16 points x 7 taps (lanes 16+ hold copies)
    int offs[7];
    {
        int p = pw + l15;
        int pe = p < N ? p : N - 1;
        offs[0] = pe * ROWB;
        const int* nb = nbrs + ((size_t)b * N + pe) * 6;
#pragma unroll
        for (int t = 1; t < 7; ++t) offs[t] = nb[t - 1] * ROWB;
    }

    float bias_v[8];
#pragma unroll
    for (int fi = 0; fi < 8; ++fi) bias_v[fi] = biasb[fi * 16 + l15];

    f32x4 acc[8];
#pragma unroll
    for (int fi = 0; fi < 8; ++fi) acc[fi] = (f32x4){0.f, 0.f, 0.f, 0.f};

    auto stage = [&](int t, int bufi) {
        char* ldsb = wavebase + bufi * WAVEBUF;
#pragma unroll
        for (int i = 0; i < NI; ++i) {
            int r    = i * (1024 / ROWB) + (lane * 16) / ROWB;  // row 0..15
            int colb = (lane * 16) & (ROWB - 1);
            int roff = __shfl(offs[t], r);
            const char* g = srcb_c + roff + (colb ^ ((r & 7) << 4));
            __builtin_amdgcn_global_load_lds(
                (const __attribute__((address_space(1))) unsigned int*)g,
                (__attribute__((address_space(3))) unsigned int*)(ldsb + i * 1024),
                16, 0, 0);
        }
    };
    auto vm_drain = [&]() {
        asm volatile("s_waitcnt vmcnt(0)" ::: "memory");
        __builtin_amdgcn_sched_barrier(0);
    };
    auto compute = [&](int t, int bufi) {
        const char* ldsb = wavebase + bufi * WAVEBUF;
#pragma unroll
        for (int kk = 0; kk < SPT; ++kk) {
            short8 a = *(const short8*)(ldsb + l15 * ROWB +
                                        ((kk * 64 + ks * 16) ^ ((l15 & 7) << 4)));
            const short8* wrow = wb + (size_t)(t * SPT + kk) * 512 + lane;
#pragma unroll
            for (int fi = 0; fi < 8; ++fi)
                acc[fi] = __builtin_amdgcn_mfma_f32_16x16x32_bf16(a, wrow[fi * 64], acc[fi], 0, 0, 0);
        }
    };

    stage(0, 0);
    vm_drain();
#pragma unroll
    for (int t = 0; t < 7; ++t) {
        if (t < 6) stage(t + 1, (t + 1) & 1);
        compute(t, t & 1);
        vm_drain();
    }

    unsigned short* dstb = dst + (size_t)b * N * LD + coff;
#pragma unroll
    for (int r = 0; r < 4; ++r) {
        int p = pw + ks * 4 + r;
        if (p < N) {
#pragma unroll
            for (int fi = 0; fi < 8; ++fi)
                dstb[(size_t)p * LD + fi * 16 + l15] = f2bf(acc[fi][r] + bias_v[fi]);
        }
    }

    if constexpr (STATS) {
        float s4[8], q4[8];
#pragma unroll
        for (int fi = 0; fi < 8; ++fi) { s4[fi] = 0.f; q4[fi] = 0.f; }
#pragma unroll
        for (int r = 0; r < 4; ++r) {
            int p = pw + ks * 4 + r;
            if (p < N) {
#pragma unroll
                for (int fi = 0; fi < 8; ++fi) {
                    float v = acc[fi][r] + bias_v[fi];
                    s4[fi] += v; q4[fi] += v * v;
                }
            }
        }
#pragma unroll
        for (int fi = 0; fi < 8; ++fi) {
            s4[fi] += __shfl_xor(s4[fi], 16); s4[fi] += __shfl_xor(s4[fi], 32);
            q4[fi] += __shfl_xor(q4[fi], 16); q4[fi] += __shfl_xor(q4[fi], 32);
        }
        __syncthreads();                       // all waves done with LDS A-bufs
        float* shs = (float*)smem;             // [4][128]
        float* shq = shs + 512;
        if (lane < 16) {
#pragma unroll
            for (int fi = 0; fi < 8; ++fi) {
                shs[wid * 128 + fi * 16 + l15] = s4[fi];
                shq[wid * 128 + fi * 16 + l15] = q4[fi];
            }
        }
        __syncthreads();
        if (threadIdx.x < 128) {
            int c = threadIdx.x;
            float ss = shs[c] + shs[128 + c] + shs[256 + c] + shs[384 + c];
            float qq = shq[c] + shq[128 + c] + shq[256 + c] + shq[384 + c];
            part[((size_t)b * gridDim.x + blockIdx.x) * 128 + c] = make_float2(ss, qq);
        }
    }
}

// ---------------- final reduce of per-block partials -> (mu, rstd) ----------------
__global__ void stats_final(const float2* __restrict__ part, float2* __restrict__ stats,
                            int N, int NB) {
    int b = blockIdx.x;
    int c = threadIdx.x & 127;
    int r = threadIdx.x >> 7;  // 0..7
    float s = 0.f, sq = 0.f;
    const float2* p = part + (size_t)b * NB * 128 + c;
#pragma unroll 4
    for (int i = r; i < NB; i += 8) {
        float2 v = p[(size_t)i * 128];
        s += v.x; sq += v.y;
    }
    __shared__ float shs[8][128], shq[8][128];
    shs[r][c] = s; shq[r][c] = sq;
    __syncthreads();
    if (r == 0) {
#pragma unroll
        for (int i = 1; i < 8; ++i) { s += shs[i][c]; sq += shq[i][c]; }
        float mu = s / N;
        float var = sq / N - mu * mu;
        stats[b * 128 + c] = make_float2(mu, rsqrtf(var + 1e-5f));
    }
}

// ---------------- final: out[b][o][n] = (z-mu2)*rstd2 + (x1-mu1)*rstd1, fp32 transposed ----------------
__global__ void final_k(const unsigned short* __restrict__ z, const unsigned short* __restrict__ x1,
                        const float2* __restrict__ stats1, const float2* __restrict__ stats2,
                        float* __restrict__ out, int N) {
    __shared__ float tile[32][33];
    int b = blockIdx.z;
    int n0 = blockIdx.x * 32, o0 = blockIdx.y * 32;
    int tx = threadIdx.x, ty = threadIdx.y;
    const unsigned short* zb = z  + (size_t)b * N * 128;
    const unsigned short* xb = x1 + (size_t)b * N * 128;
    float2 st1 = stats1[b * 128 + o0 + tx];
    float2 st2 = stats2[b * 128 + o0 + tx];
#pragma unroll
    for (int i = 0; i < 32; i += 8) {
        int n = n0 + ty + i;
        float v = 0.f;
        if (n < N) {
            float zv = bf2f(zb[(size_t)n * 128 + o0 + tx]);
            float xv = bf2f(xb[(size_t)n * 128 + o0 + tx]);
            v = (zv - st2.x) * st2.y + (xv - st1.x) * st1.y;
        }
        tile[ty + i][tx] = v;
    }
    __syncthreads();
    float* ob = out + (size_t)b * 128 * N;
#pragma unroll
    for (int i = 0; i < 32; i += 8) {
        int o = o0 + ty + i, n = n0 + tx;
        if (n < N) ob[(size_t)o * N + n] = tile[tx][ty + i];
    }
}

extern "C" void kernel_launch(void* const* d_in, const int* in_sizes, int n_in,
                              void* d_out, int out_size, void* d_ws, size_t ws_size,
                              hipStream_t stream) {
    const float* from_up   = (const float*)d_in[0];  // [2,256,30000]
    const float* from_down = (const float*)d_in[1];  // [2,128,30000]
    const int*   neighbors = (const int*)d_in[2];    // [2,30000,6]
    const float* W_up = (const float*)d_in[3];
    const float* b_up = (const float*)d_in[4];
    const float* W_1  = (const float*)d_in[5];
    const float* b_1  = (const float*)d_in[6];
    const float* W_2  = (const float*)d_in[7];
    const float* b_2  = (const float*)d_in[8];
    float* out = (float*)d_out;

    const int B = 2, N = 30000;
    const int S1 = 56, S3 = 28;        // K-steps: 1792/32, 896/32
    const int NBLK = (N + 63) / 64;    // 469 conv blocks per batch

    char* ws = (char*)d_ws;
    size_t off = 0;
    auto alloc = [&](size_t bytes) {
        char* p = ws + off;
        off += (bytes + 255) & ~(size_t)255;
        return p;
    };
    unsigned short* upT   = (unsigned short*)alloc((size_t)B * N * 256 * 2);
    unsigned short* catT  = (unsigned short*)alloc((size_t)B * N * 256 * 2);
    unsigned short* x1    = (unsigned short*)alloc((size_t)B * N * 128 * 2);
    unsigned short* Wp0   = (unsigned short*)alloc((size_t)S1 * 512 * 8 * 2);
    unsigned short* Wp1   = (unsigned short*)alloc((size_t)S1 * 512 * 8 * 2);
    unsigned short* Wp2b  = (unsigned short*)alloc((size_t)B * S3 * 512 * 8 * 2);
    float*  b2fold = (float*)alloc((size_t)B * 128 * 4);
    float2* part   = (float2*)alloc((size_t)B * NBLK * 128 * 8);
    float2* stats1 = (float2*)alloc((size_t)B * 128 * 8);
    float2* stats2 = (float2*)alloc((size_t)B * 128 * 8);
    unsigned short* zbuf = upT;  // reuse (upT dead after conv1)

    // prepack static weights
    prepack_w<<<(S1 * 512 + 255) / 256, 256, 0, stream>>>(W_up, Wp0, 256, S1);
    prepack_w<<<(S1 * 512 + 255) / 256, 256, 0, stream>>>(W_1,  Wp1, 256, S1);

    // transpose inputs to [B][N][C] bf16
    dim3 tb(32, 8);
    transpose_cast<<<dim3((N + 31) / 32, 256 / 32, B), tb, 0, stream>>>(from_up, upT, 256, N, 256, 0);
    transpose_cast<<<dim3((N + 31) / 32, 128 / 32, B), tb, 0, stream>>>(from_down, catT, 128, N, 256, 128);

    dim3 cgrid(NBLK, B);
    // conv1: upT (Cin=256) -> catT[:, 0:128]
    conv_lds<256, 256, false><<<cgrid, 256, 0, stream>>>(
        upT, neighbors, Wp0, 0, b_up, 0, catT, nullptr, N, 0);
    // conv2: catT (Cin=256) -> x1, fused stats partials
    conv_lds<256, 128, true><<<cgrid, 256, 0, stream>>>(
        catT, neighbors, Wp1, 0, b_1, 0, x1, part, N, 0);
    stats_final<<<B, 1024, 0, stream>>>((const float2*)part, stats1, N, NBLK);

    // fold norm1 into conv3's weights/bias (per batch)
    prepack_w_scaled<<<(B * S3 * 512 + 255) / 256, 256, 0, stream>>>(W_2, stats1, Wp2b, 128, S3);
    fold_bias2<<<B, 128, 0, stream>>>(W_2, b_2, stats1, b2fold);

    // conv3: x1 (Cin=128, scaled weights) -> zbuf, fused stats partials
    conv_lds<128, 128, true><<<cgrid, 256, 0, stream>>>(
        x1, neighbors, Wp2b, (size_t)S3 * 512, b2fold, 128, zbuf, part, N, 0);
    stats_final<<<B, 1024, 0, stream>>>((const float2*)part, stats2, N, NBLK);

    // final: normalize z, add recomputed x1n, transpose to [B][128][N] fp32
    final_k<<<dim3((N + 31) / 32, 4, B), tb, 0, stream>>>(zbuf, x1, stats1, stats2, out, N);
}

// Round 7
// 227.974 us; speedup vs baseline: 1.2990x; 1.2990x over previous
//
#include <hip/hip_runtime.h>

typedef __attribute__((ext_vector_type(8))) short short8;
typedef __attribute__((ext_vector_type(4))) float f32x4;

static __device__ __forceinline__ float bf2f(unsigned short u) {
    unsigned int x = ((unsigned int)u) << 16;
    union { unsigned int i; float f; } c; c.i = x; return c.f;
}
static __device__ __forceinline__ unsigned short f2bf(float f) {
    union { float f; unsigned int i; } c; c.f = f;
    unsigned int x = c.i;
    unsigned int r = (x + 0x7FFFu + ((x >> 16) & 1u)) >> 16;
    return (unsigned short)r;
}
static __device__ __forceinline__ void glds16(const char* g, char* l) {
    __builtin_amdgcn_global_load_lds(
        (const __attribute__((address_space(1))) unsigned int*)g,
        (__attribute__((address_space(3))) unsigned int*)l, 16, 0, 0);
}

// ---------------- prepack W [Cout=128][Cin][7] fp32 -> fragment-linear bf16 ----------------
__global__ void prepack_w(const float* __restrict__ W, unsigned short* __restrict__ Wp,
                          int Cin, int S) {
    int tid = blockIdx.x * blockDim.x + threadIdx.x;
    if (tid >= S * 512) return;
    int lane = tid & 63;
    int f = (tid >> 6) & 7;
    int s = tid >> 9;
    int o = f * 16 + (lane & 15);
    int kbase = s * 32 + 8 * (lane >> 4);
    unsigned short* dst = Wp + (size_t)tid * 8;
#pragma unroll
    for (int j = 0; j < 8; ++j) {
        int kk = kbase + j;
        int t = kk / Cin;
        int c = kk - t * Cin;
        dst[j] = f2bf(W[((size_t)o * Cin + c) * 7 + t]);
    }
}

__global__ void prepack_w_scaled(const float* __restrict__ W, const float2* __restrict__ stats,
                                 unsigned short* __restrict__ Wp, int Cin, int S) {
    int tid = blockIdx.x * blockDim.x + threadIdx.x;
    if (tid >= 2 * S * 512) return;
    int b = tid / (S * 512);
    int rem = tid - b * S * 512;
    int lane = rem & 63;
    int f = (rem >> 6) & 7;
    int s = rem >> 9;
    int o = f * 16 + (lane & 15);
    int kbase = s * 32 + 8 * (lane >> 4);
    unsigned short* dst = Wp + (size_t)tid * 8;
#pragma unroll
    for (int j = 0; j < 8; ++j) {
        int kk = kbase + j;
        int t = kk / Cin;
        int c = kk - t * Cin;
        float scale = stats[b * 128 + c].y;
        dst[j] = f2bf(W[((size_t)o * Cin + c) * 7 + t] * scale);
    }
}

__global__ void fold_bias2(const float* __restrict__ W2, const float* __restrict__ b2,
                           const float2* __restrict__ stats, float* __restrict__ b2out) {
    int b = blockIdx.x, o = threadIdx.x;
    float sum = 0.f;
    for (int c = 0; c < 128; ++c) {
        float2 st = stats[b * 128 + c];
        float sm = st.x * st.y;
        float ws = 0.f;
#pragma unroll
        for (int t = 0; t < 7; ++t) ws += W2[((size_t)o * 128 + c) * 7 + t];
        sum += ws * sm;
    }
    b2out[b * 128 + o] = b2[o] - sum;
}

// ---------------- transpose fp32 [B][C][N] -> bf16 [B][N][ldo] at column offset ----------------
__global__ void transpose_cast(const float* __restrict__ in, unsigned short* __restrict__ out,
                               int C, int N, int ldo, int coff) {
    __shared__ float tile[32][33];
    int b = blockIdx.z;
    int n0 = blockIdx.x * 32;
    int c0 = blockIdx.y * 32;
    const float* inb = in + (size_t)b * C * N;
    unsigned short* outb = out + (size_t)b * N * ldo;
    int tx = threadIdx.x, ty = threadIdx.y;
#pragma unroll
    for (int i = 0; i < 32; i += 8) {
        int c = c0 + ty + i, n = n0 + tx;
        float v = 0.f;
        if (n < N) v = inb[(size_t)c * N + n];
        tile[ty + i][tx] = v;
    }
    __syncthreads();
#pragma unroll
    for (int i = 0; i < 32; i += 8) {
        int n = n0 + ty + i, c = c0 + tx;
        if (n < N) outb[(size_t)n * ldo + coff + c] = f2bf(tile[tx][ty + i]);
    }
}

// ---------------- GEMM-ified gather-conv: A and W both LDS-staged ----------------
// Block: 64 points x 128 couts, 2 waves (wave = 64 pts x 64 couts, acc 4x4 frags).
// K-loop (BK=32): A slice = 64 rows x 64B (4KB), W slice = 8KB. 4-buf rotation,
// depth-2 prefetch, counted vmcnt(12), one s_barrier per k-step. Each wave issues
// exactly 6 global_load_lds per k-step (w0: 4A+2W, w1: 6W) so vmcnt is wave-exact.
template<int CS, int LD, bool STATS>
__global__ __launch_bounds__(128, 2) void conv_gemm(
    const unsigned short* __restrict__ src,
    const int* __restrict__ nbrs,
    const unsigned short* __restrict__ Wp, size_t w_bstride_bytes,
    const float* __restrict__ bias, int bias_bstride,
    unsigned short* __restrict__ dst,
    float2* __restrict__ part,
    int N, int coff)
{
    constexpr int ROWB = CS * 2;
    constexpr int SPT  = CS / 32;   // k-steps per tap
    constexpr int S    = SPT * 7;   // total k-steps

    const int tid  = threadIdx.x;
    const int lane = tid & 63;
    const int wid  = tid >> 6;      // cout half
    const int l15  = lane & 15;
    const int ks   = lane >> 4;
    const int b    = blockIdx.y;
    const int pblk = blockIdx.x * 64;

    const char* srcb = (const char*)src + (size_t)b * N * ROWB;
    const char* wbc  = (const char*)Wp + (size_t)b * w_bstride_bytes;

    __shared__ char smem[4 * 4096 + 4 * 8192];  // A bufs @0 (16KB), W bufs @16KB (32KB)

    // --- prologue: per-lane row offsets, pre-shfl'ed per stage-instr, then full drain ---
    int roffA[28];
    if (wid == 0) {
        int p = pblk + lane;
        int pe = p < N ? p : N - 1;
        int offs[7];
        offs[0] = pe * ROWB;
        const int* nb = nbrs + ((size_t)b * N + pe) * 6;
#pragma unroll
        for (int t = 1; t < 7; ++t) offs[t] = nb[t - 1] * ROWB;
#pragma unroll
        for (int t = 0; t < 7; ++t)
#pragma unroll
            for (int i = 0; i < 4; ++i)
                roffA[t * 4 + i] = __shfl(offs[t], i * 16 + (lane >> 2));
    }
    asm volatile("s_waitcnt vmcnt(0)" ::: "memory");
    __builtin_amdgcn_sched_barrier(0);

    const int asw = ((lane & 3) ^ ((lane >> 2) & 3)) << 4;  // source-side XOR swizzle

    auto stage_all = [&](int t, int kk, int s, int buf) {
        if (wid == 0) {
#pragma unroll
            for (int i = 0; i < 4; ++i)
                glds16(srcb + roffA[t * 4 + i] + kk * 64 + asw,
                       smem + buf * 4096 + i * 1024);
            const char* gw = wbc + (size_t)s * 8192 + lane * 16;
#pragma unroll
            for (int i = 0; i < 2; ++i)
                glds16(gw + i * 1024, smem + 16384 + buf * 8192 + i * 1024);
        } else {
            const char* gw = wbc + (size_t)s * 8192 + lane * 16;
#pragma unroll
            for (int i = 2; i < 8; ++i)
                glds16(gw + i * 1024, smem + 16384 + buf * 8192 + i * 1024);
        }
    };

    f32x4 acc[4][4];
#pragma unroll
    for (int rg = 0; rg < 4; ++rg)
#pragma unroll
        for (int fi = 0; fi < 4; ++fi) acc[rg][fi] = (f32x4){0.f, 0.f, 0.f, 0.f};

    stage_all(0, 0, 0, 0);
    stage_all(0, 1, 1, 1);

#pragma unroll
    for (int t = 0; t < 7; ++t) {
#pragma unroll
        for (int kk = 0; kk < SPT; ++kk) {
            const int s = t * SPT + kk;
            if (s + 2 < S) {
                const int s2 = s + 2;
                stage_all(s2 / SPT, s2 % SPT, s2, s2 & 3);
            }
            if (s + 2 < S)      { asm volatile("s_waitcnt vmcnt(12)" ::: "memory"); }
            else if (s + 1 < S) { asm volatile("s_waitcnt vmcnt(6)" ::: "memory"); }
            else                { asm volatile("s_waitcnt vmcnt(0)" ::: "memory"); }
            __builtin_amdgcn_sched_barrier(0);
            __builtin_amdgcn_s_barrier();
            __builtin_amdgcn_sched_barrier(0);

            const char* Ab = smem + (s & 3) * 4096;
            const char* Wb = smem + 16384 + (s & 3) * 8192;
            short8 a[4], w[4];
#pragma unroll
            for (int rg = 0; rg < 4; ++rg)
                a[rg] = *(const short8*)(Ab + (rg * 16 + l15) * 64 +
                                         ((ks * 16) ^ ((l15 & 3) << 4)));
#pragma unroll
            for (int fi = 0; fi < 4; ++fi)
                w[fi] = *(const short8*)(Wb + (wid * 4 + fi) * 1024 + lane * 16);
#pragma unroll
            for (int rg = 0; rg < 4; ++rg)
#pragma unroll
                for (int fi = 0; fi < 4; ++fi)
                    acc[rg][fi] = __builtin_amdgcn_mfma_f32_16x16x32_bf16(
                        a[rg], w[fi], acc[rg][fi], 0, 0, 0);
        }
    }

    // --- epilogue: bias, store bf16, fused stats ---
    const float* biasb = bias + (size_t)b * bias_bstride + wid * 64;
    float bias_v[4];
#pragma unroll
    for (int fi = 0; fi < 4; ++fi) bias_v[fi] = biasb[fi * 16 + l15];

    unsigned short* dstb = dst + (size_t)b * N * LD + coff + wid * 64;
#pragma unroll
    for (int rg = 0; rg < 4; ++rg) {
#pragma unroll
        for (int r = 0; r < 4; ++r) {
            int p = pblk + rg * 16 + ks * 4 + r;
            if (p < N) {
#pragma unroll
                for (int fi = 0; fi < 4; ++fi)
                    dstb[(size_t)p * LD + fi * 16 + l15] = f2bf(acc[rg][fi][r] + bias_v[fi]);
            }
        }
    }

    if constexpr (STATS) {
        float s4[4], q4[4];
#pragma unroll
        for (int fi = 0; fi < 4; ++fi) { s4[fi] = 0.f; q4[fi] = 0.f; }
#pragma unroll
        for (int rg = 0; rg < 4; ++rg) {
#pragma unroll
            for (int r = 0; r < 4; ++r) {
                int p = pblk + rg * 16 + ks * 4 + r;
                if (p < N) {
#pragma unroll
                    for (int fi = 0; fi < 4; ++fi) {
                        float v = acc[rg][fi][r] + bias_v[fi];
                        s4[fi] += v; q4[fi] += v * v;
                    }
                }
            }
        }
#pragma unroll
        for (int fi = 0; fi < 4; ++fi) {
            s4[fi] += __shfl_xor(s4[fi], 16); s4[fi] += __shfl_xor(s4[fi], 32);
            q4[fi] += __shfl_xor(q4[fi], 16); q4[fi] += __shfl_xor(q4[fi], 32);
        }
        __syncthreads();
        float* shs = (float*)smem;       // [2][64]
        float* shq = shs + 128;
        if (lane < 16) {
#pragma unroll
            for (int fi = 0; fi < 4; ++fi) {
                shs[wid * 64 + fi * 16 + l15] = s4[fi];
                shq[wid * 64 + fi * 16 + l15] = q4[fi];
            }
        }
        __syncthreads();
        if (tid < 128) {
            int c = tid;
            part[((size_t)b * gridDim.x + blockIdx.x) * 128 + c] =
                make_float2(shs[c], shq[c]);
        }
    }
}

// ---------------- final reduce of per-block partials -> (mu, rstd) ----------------
__global__ void stats_final(const float2* __restrict__ part, float2* __restrict__ stats,
                            int N, int NB) {
    int b = blockIdx.x;
    int c = threadIdx.x & 127;
    int r = threadIdx.x >> 7;  // 0..7
    float s = 0.f, sq = 0.f;
    const float2* p = part + (size_t)b * NB * 128 + c;
#pragma unroll 4
    for (int i = r; i < NB; i += 8) {
        float2 v = p[(size_t)i * 128];
        s += v.x; sq += v.y;
    }
    __shared__ float shs[8][128], shq[8][128];
    shs[r][c] = s; shq[r][c] = sq;
    __syncthreads();
    if (r == 0) {
#pragma unroll
        for (int i = 1; i < 8; ++i) { s += shs[i][c]; sq += shq[i][c]; }
        float mu = s / N;
        float var = sq / N - mu * mu;
        stats[b * 128 + c] = make_float2(mu, rsqrtf(var + 1e-5f));
    }
}

// ---------------- final: out[b][o][n] = (z-mu2)*rstd2 + (x1-mu1)*rstd1, fp32 transposed ----------------
__global__ void final_k(const unsigned short* __restrict__ z, const unsigned short* __restrict__ x1,
                        const float2* __restrict__ stats1, const float2* __restrict__ stats2,
                        float* __restrict__ out, int N) {
    __shared__ float tile[32][33];
    int b = blockIdx.z;
    int n0 = blockIdx.x * 32, o0 = blockIdx.y * 32;
    int tx = threadIdx.x, ty = threadIdx.y;
    const unsigned short* zb = z  + (size_t)b * N * 128;
    const unsigned short* xb = x1 + (size_t)b * N * 128;
    float2 st1 = stats1[b * 128 + o0 + tx];
    float2 st2 = stats2[b * 128 + o0 + tx];
#pragma unroll
    for (int i = 0; i < 32; i += 8) {
        int n = n0 + ty + i;
        float v = 0.f;
        if (n < N) {
            float zv = bf2f(zb[(size_t)n * 128 + o0 + tx]);
            float xv = bf2f(xb[(size_t)n * 128 + o0 + tx]);
            v = (zv - st2.x) * st2.y + (xv - st1.x) * st1.y;
        }
        tile[ty + i][tx] = v;
    }
    __syncthreads();
    float* ob = out + (size_t)b * 128 * N;
#pragma unroll
    for (int i = 0; i < 32; i += 8) {
        int o = o0 + ty + i, n = n0 + tx;
        if (n < N) ob[(size_t)o * N + n] = tile[tx][ty + i];
    }
}

extern "C" void kernel_launch(void* const* d_in, const int* in_sizes, int n_in,
                              void* d_out, int out_size, void* d_ws, size_t ws_size,
                              hipStream_t stream) {
    const float* from_up   = (const float*)d_in[0];  // [2,256,30000]
    const float* from_down = (const float*)d_in[1];  // [2,128,30000]
    const int*   neighbors = (const int*)d_in[2];    // [2,30000,6]
    const float* W_up = (const float*)d_in[3];
    const float* b_up = (const float*)d_in[4];
    const float* W_1  = (const float*)d_in[5];
    const float* b_1  = (const float*)d_in[6];
    const float* W_2  = (const float*)d_in[7];
    const float* b_2  = (const float*)d_in[8];
    float* out = (float*)d_out;

    const int B = 2, N = 30000;
    const int S1 = 56, S3 = 28;        // K-steps: 1792/32, 896/32
    const int NBLK = (N + 63) / 64;    // 469 conv blocks per batch

    char* ws = (char*)d_ws;
    size_t off = 0;
    auto alloc = [&](size_t bytes) {
        char* p = ws + off;
        off += (bytes + 255) & ~(size_t)255;
        return p;
    };
    unsigned short* upT   = (unsigned short*)alloc((size_t)B * N * 256 * 2);
    unsigned short* catT  = (unsigned short*)alloc((size_t)B * N * 256 * 2);
    unsigned short* x1    = (unsigned short*)alloc((size_t)B * N * 128 * 2);
    unsigned short* Wp0   = (unsigned short*)alloc((size_t)S1 * 512 * 8 * 2);
    unsigned short* Wp1   = (unsigned short*)alloc((size_t)S1 * 512 * 8 * 2);
    unsigned short* Wp2b  = (unsigned short*)alloc((size_t)B * S3 * 512 * 8 * 2);
    float*  b2fold = (float*)alloc((size_t)B * 128 * 4);
    float2* part   = (float2*)alloc((size_t)B * NBLK * 128 * 8);
    float2* stats1 = (float2*)alloc((size_t)B * 128 * 8);
    float2* stats2 = (float2*)alloc((size_t)B * 128 * 8);
    unsigned short* zbuf = upT;  // reuse (upT dead after conv1)

    // prepack static weights
    prepack_w<<<(S1 * 512 + 255) / 256, 256, 0, stream>>>(W_up, Wp0, 256, S1);
    prepack_w<<<(S1 * 512 + 255) / 256, 256, 0, stream>>>(W_1,  Wp1, 256, S1);

    // transpose inputs to [B][N][C] bf16
    dim3 tb(32, 8);
    transpose_cast<<<dim3((N + 31) / 32, 256 / 32, B), tb, 0, stream>>>(from_up, upT, 256, N, 256, 0);
    transpose_cast<<<dim3((N + 31) / 32, 128 / 32, B), tb, 0, stream>>>(from_down, catT, 128, N, 256, 128);

    dim3 cgrid(NBLK, B);
    // conv1: upT (Cin=256) -> catT[:, 0:128]
    conv_gemm<256, 256, false><<<cgrid, 128, 0, stream>>>(
        upT, neighbors, Wp0, 0, b_up, 0, catT, nullptr, N, 0);
    // conv2: catT (Cin=256) -> x1, fused stats partials
    conv_gemm<256, 128, true><<<cgrid, 128, 0, stream>>>(
        catT, neighbors, Wp1, 0, b_1, 0, x1, part, N, 0);
    stats_final<<<B, 1024, 0, stream>>>((const float2*)part, stats1, N, NBLK);

    // fold norm1 into conv3's weights/bias (per batch)
    prepack_w_scaled<<<(B * S3 * 512 + 255) / 256, 256, 0, stream>>>(W_2, stats1, Wp2b, 128, S3);
    fold_bias2<<<B, 128, 0, stream>>>(W_2, b_2, stats1, b2fold);

    // conv3: x1 (Cin=128, scaled weights) -> zbuf, fused stats partials
    conv_gemm<128, 128, true><<<cgrid, 128, 0, stream>>>(
        x1, neighbors, Wp2b, (size_t)S3 * 512 * 16, b2fold, 128, zbuf, part, N, 0);
    stats_final<<<B, 1024, 0, stream>>>((const float2*)part, stats2, N, NBLK);

    // final: normalize z, add recomputed x1n, transpose to [B][128][N] fp32
    final_k<<<dim3((N + 31) / 32, 4, B), tb, 0, stream>>>(zbuf, x1, stats1, stats2, out, N);
}

// Round 8
// 188.380 us; speedup vs baseline: 1.5720x; 1.2102x over previous
//
#include <hip/hip_runtime.h>

typedef __attribute__((ext_vector_type(8))) short short8;
typedef __attribute__((ext_vector_type(4))) float f32x4;

static __device__ __forceinline__ float bf2f(unsigned short u) {
    unsigned int x = ((unsigned int)u) << 16;
    union { unsigned int i; float f; } c; c.i = x; return c.f;
}
static __device__ __forceinline__ unsigned short f2bf(float f) {
    union { float f; unsigned int i; } c; c.f = f;
    unsigned int x = c.i;
    unsigned int r = (x + 0x7FFFu + ((x >> 16) & 1u)) >> 16;
    return (unsigned short)r;
}
static __device__ __forceinline__ void glds16(const char* g, char* l) {
    __builtin_amdgcn_global_load_lds(
        (const __attribute__((address_space(1))) unsigned int*)g,
        (__attribute__((address_space(3))) unsigned int*)l, 16, 0, 0);
}

// ---------------- prepack W [Cout=128][Cin][7] fp32 -> fragment-linear bf16 ----------------
__global__ void prepack_w(const float* __restrict__ W, unsigned short* __restrict__ Wp,
                          int Cin, int S) {
    int tid = blockIdx.x * blockDim.x + threadIdx.x;
    if (tid >= S * 512) return;
    int lane = tid & 63;
    int f = (tid >> 6) & 7;
    int s = tid >> 9;
    int o = f * 16 + (lane & 15);
    int kbase = s * 32 + 8 * (lane >> 4);
    unsigned short* dst = Wp + (size_t)tid * 8;
#pragma unroll
    for (int j = 0; j < 8; ++j) {
        int kk = kbase + j;
        int t = kk / Cin;
        int c = kk - t * Cin;
        dst[j] = f2bf(W[((size_t)o * Cin + c) * 7 + t]);
    }
}

__global__ void prepack_w_scaled(const float* __restrict__ W, const float2* __restrict__ stats,
                                 unsigned short* __restrict__ Wp, int Cin, int S) {
    int tid = blockIdx.x * blockDim.x + threadIdx.x;
    if (tid >= 2 * S * 512) return;
    int b = tid / (S * 512);
    int rem = tid - b * S * 512;
    int lane = rem & 63;
    int f = (rem >> 6) & 7;
    int s = rem >> 9;
    int o = f * 16 + (lane & 15);
    int kbase = s * 32 + 8 * (lane >> 4);
    unsigned short* dst = Wp + (size_t)tid * 8;
#pragma unroll
    for (int j = 0; j < 8; ++j) {
        int kk = kbase + j;
        int t = kk / Cin;
        int c = kk - t * Cin;
        float scale = stats[b * 128 + c].y;
        dst[j] = f2bf(W[((size_t)o * Cin + c) * 7 + t] * scale);
    }
}

__global__ void fold_bias2(const float* __restrict__ W2, const float* __restrict__ b2,
                           const float2* __restrict__ stats, float* __restrict__ b2out) {
    int b = blockIdx.x, o = threadIdx.x;
    float sum = 0.f;
    for (int c = 0; c < 128; ++c) {
        float2 st = stats[b * 128 + c];
        float sm = st.x * st.y;
        float ws = 0.f;
#pragma unroll
        for (int t = 0; t < 7; ++t) ws += W2[((size_t)o * 128 + c) * 7 + t];
        sum += ws * sm;
    }
    b2out[b * 128 + o] = b2[o] - sum;
}

// ---------------- transpose fp32 [B][C][N] -> bf16 [B][N][ldo] at column offset ----------------
__global__ void transpose_cast(const float* __restrict__ in, unsigned short* __restrict__ out,
                               int C, int N, int ldo, int coff) {
    __shared__ float tile[32][33];
    int b = blockIdx.z;
    int n0 = blockIdx.x * 32;
    int c0 = blockIdx.y * 32;
    const float* inb = in + (size_t)b * C * N;
    unsigned short* outb = out + (size_t)b * N * ldo;
    int tx = threadIdx.x, ty = threadIdx.y;
#pragma unroll
    for (int i = 0; i < 32; i += 8) {
        int c = c0 + ty + i, n = n0 + tx;
        float v = 0.f;
        if (n < N) v = inb[(size_t)c * N + n];
        tile[ty + i][tx] = v;
    }
    __syncthreads();
#pragma unroll
    for (int i = 0; i < 32; i += 8) {
        int n = n0 + ty + i, c = c0 + tx;
        if (n < N) outb[(size_t)n * ldo + coff + c] = f2bf(tile[tx][ty + i]);
    }
}

// ---------------- GEMM-ified gather-conv: A and W both LDS-staged ----------------
// Block: 128 points x 128 couts, 4 waves (wave = 64 pts (pg) x 64 couts (h)).
// K-loop (BK=32): A = 128 rows x 64B (8KB), W = 8KB. 4-buf rotation, depth-2
// prefetch, counted vmcnt(8), one s_barrier per k-step. Staging: wid0/1 = A
// halves, wid2/3 = W halves -> exactly 4 global_load_lds per wave per k-step.
template<int CS, int LD, bool STATS>
__global__ __launch_bounds__(256, 2) void conv_gemm(
    const unsigned short* __restrict__ src,
    const int* __restrict__ nbrs,
    const unsigned short* __restrict__ Wp, size_t w_bstride_bytes,
    const float* __restrict__ bias, int bias_bstride,
    unsigned short* __restrict__ dst,
    float2* __restrict__ part,
    int N, int coff)
{
    constexpr int ROWB = CS * 2;
    constexpr int SPT  = CS / 32;   // k-steps per tap
    constexpr int S    = SPT * 7;   // total k-steps

    const int tid  = threadIdx.x;
    const int lane = tid & 63;
    const int wid  = tid >> 6;
    const int pg   = wid & 1;       // point half (compute)
    const int h    = wid >> 1;      // cout half (compute)
    const int l15  = lane & 15;
    const int ks   = lane >> 4;
    const int b    = blockIdx.y;
    const int pblk = blockIdx.x * 128;

    const char* srcb = (const char*)src + (size_t)b * N * ROWB;
    const char* wbc  = (const char*)Wp + (size_t)b * w_bstride_bytes;

    __shared__ char smem[4 * 8192 + 4 * 8192];  // A bufs 32KB @0, W bufs 32KB @32768

    // --- prologue: staging row offsets (wid0: rows 0-63, wid1: rows 64-127) ---
    int roffA[28];
    if (wid < 2) {
        int p = pblk + wid * 64 + lane;
        int pe = p < N ? p : N - 1;
        int offs[7];
        offs[0] = pe * ROWB;
        const int* nb = nbrs + ((size_t)b * N + pe) * 6;
#pragma unroll
        for (int t = 1; t < 7; ++t) offs[t] = nb[t - 1] * ROWB;
#pragma unroll
        for (int t = 0; t < 7; ++t)
#pragma unroll
            for (int i = 0; i < 4; ++i)
                roffA[t * 4 + i] = __shfl(offs[t], i * 16 + (lane >> 2));
    }
    asm volatile("s_waitcnt vmcnt(0)" ::: "memory");
    __builtin_amdgcn_sched_barrier(0);

    // source-side XOR swizzle: granule (lane&3) stores global granule
    // (lane&3) ^ f(r), f(r) = (r&3)^((r>>2)&3), r = chunk-row = lane>>2 (+16i)
    const int asw = (((lane & 3) ^ ((lane >> 2) & 3) ^ ((lane >> 4) & 3)) << 4);

    auto stage_all = [&](int t, int kk, int s, int buf) {
        if (wid < 2) {
#pragma unroll
            for (int i = 0; i < 4; ++i)
                glds16(srcb + roffA[t * 4 + i] + kk * 64 + asw,
                       smem + buf * 8192 + wid * 4096 + i * 1024);
        } else {
            const char* gw = wbc + (size_t)s * 8192 + (wid - 2) * 4096 + lane * 16;
            char* lw = smem + 32768 + buf * 8192 + (wid - 2) * 4096;
#pragma unroll
            for (int i = 0; i < 4; ++i)
                glds16(gw + i * 1024, lw + i * 1024);
        }
    };

    f32x4 acc[4][4];
#pragma unroll
    for (int rg = 0; rg < 4; ++rg)
#pragma unroll
        for (int fi = 0; fi < 4; ++fi) acc[rg][fi] = (f32x4){0.f, 0.f, 0.f, 0.f};

    stage_all(0, 0, 0, 0);
    stage_all(1 / SPT, 1 % SPT, 1, 1);

    const int arsw = (((l15 & 3) ^ ((l15 >> 2) & 3)) << 4);  // f(row)<<4 on read side

#pragma unroll
    for (int t = 0; t < 7; ++t) {
#pragma unroll
        for (int kk = 0; kk < SPT; ++kk) {
            const int s = t * SPT + kk;
            if (s + 2 < S) {
                const int s2 = s + 2;
                stage_all(s2 / SPT, s2 % SPT, s2, s2 & 3);
            }
            if (s + 2 < S)      { asm volatile("s_waitcnt vmcnt(8)" ::: "memory"); }
            else if (s + 1 < S) { asm volatile("s_waitcnt vmcnt(4)" ::: "memory"); }
            else                { asm volatile("s_waitcnt vmcnt(0)" ::: "memory"); }
            __builtin_amdgcn_sched_barrier(0);
            __builtin_amdgcn_s_barrier();
            __builtin_amdgcn_sched_barrier(0);

            const char* Ab = smem + (s & 3) * 8192;
            const char* Wb = smem + 32768 + (s & 3) * 8192;
            short8 a[4], w[4];
#pragma unroll
            for (int rg = 0; rg < 4; ++rg)
                a[rg] = *(const short8*)(Ab + (pg * 64 + rg * 16 + l15) * 64 +
                                         ((ks << 4) ^ arsw));
#pragma unroll
            for (int fi = 0; fi < 4; ++fi)
                w[fi] = *(const short8*)(Wb + (h * 4 + fi) * 1024 + lane * 16);
            __builtin_amdgcn_s_setprio(1);
#pragma unroll
            for (int rg = 0; rg < 4; ++rg)
#pragma unroll
                for (int fi = 0; fi < 4; ++fi)
                    acc[rg][fi] = __builtin_amdgcn_mfma_f32_16x16x32_bf16(
                        a[rg], w[fi], acc[rg][fi], 0, 0, 0);
            __builtin_amdgcn_s_setprio(0);
        }
    }

    // --- epilogue: bias, store bf16, fused stats ---
    const float* biasb = bias + (size_t)b * bias_bstride + h * 64;
    float bias_v[4];
#pragma unroll
    for (int fi = 0; fi < 4; ++fi) bias_v[fi] = biasb[fi * 16 + l15];

    unsigned short* dstb = dst + (size_t)b * N * LD + coff + h * 64;
#pragma unroll
    for (int rg = 0; rg < 4; ++rg) {
#pragma unroll
        for (int r = 0; r < 4; ++r) {
            int p = pblk + pg * 64 + rg * 16 + ks * 4 + r;
            if (p < N) {
#pragma unroll
                for (int fi = 0; fi < 4; ++fi)
                    dstb[(size_t)p * LD + fi * 16 + l15] = f2bf(acc[rg][fi][r] + bias_v[fi]);
            }
        }
    }

    if constexpr (STATS) {
        float s4[4], q4[4];
#pragma unroll
        for (int fi = 0; fi < 4; ++fi) { s4[fi] = 0.f; q4[fi] = 0.f; }
#pragma unroll
        for (int rg = 0; rg < 4; ++rg) {
#pragma unroll
            for (int r = 0; r < 4; ++r) {
                int p = pblk + pg * 64 + rg * 16 + ks * 4 + r;
                if (p < N) {
#pragma unroll
                    for (int fi = 0; fi < 4; ++fi) {
                        float v = acc[rg][fi][r] + bias_v[fi];
                        s4[fi] += v; q4[fi] += v * v;
                    }
                }
            }
        }
#pragma unroll
        for (int fi = 0; fi < 4; ++fi) {
            s4[fi] += __shfl_xor(s4[fi], 16); s4[fi] += __shfl_xor(s4[fi], 32);
            q4[fi] += __shfl_xor(q4[fi], 16); q4[fi] += __shfl_xor(q4[fi], 32);
        }
        __syncthreads();
        float* shs = (float*)smem;       // [4][64]
        float* shq = shs + 256;
        if (lane < 16) {
#pragma unroll
            for (int fi = 0; fi < 4; ++fi) {
                shs[wid * 64 + fi * 16 + l15] = s4[fi];
                shq[wid * 64 + fi * 16 + l15] = q4[fi];
            }
        }
        __syncthreads();
        if (tid < 128) {
            int c = tid;
            int hh = c >> 6, cl = c & 63;   // waves 2*hh (pg0) and 2*hh+1 (pg1)
            float ss = shs[(2 * hh) * 64 + cl] + shs[(2 * hh + 1) * 64 + cl];
            float qq = shq[(2 * hh) * 64 + cl] + shq[(2 * hh + 1) * 64 + cl];
            part[((size_t)b * gridDim.x + blockIdx.x) * 128 + c] = make_float2(ss, qq);
        }
    }
}

// ---------------- final reduce of per-block partials -> (mu, rstd) ----------------
__global__ void stats_final(const float2* __restrict__ part, float2* __restrict__ stats,
                            int N, int NB) {
    int b = blockIdx.x;
    int c = threadIdx.x & 127;
    int r = threadIdx.x >> 7;  // 0..7
    float s = 0.f, sq = 0.f;
    const float2* p = part + (size_t)b * NB * 128 + c;
#pragma unroll 4
    for (int i = r; i < NB; i += 8) {
        float2 v = p[(size_t)i * 128];
        s += v.x; sq += v.y;
    }
    __shared__ float shs[8][128], shq[8][128];
    shs[r][c] = s; shq[r][c] = sq;
    __syncthreads();
    if (r == 0) {
#pragma unroll
        for (int i = 1; i < 8; ++i) { s += shs[i][c]; sq += shq[i][c]; }
        float mu = s / N;
        float var = sq / N - mu * mu;
        stats[b * 128 + c] = make_float2(mu, rsqrtf(var + 1e-5f));
    }
}

// ---------------- final: out[b][o][n] = (z-mu2)*rstd2 + (x1-mu1)*rstd1, fp32 transposed ----------------
__global__ void final_k(const unsigned short* __restrict__ z, const unsigned short* __restrict__ x1,
                        const float2* __restrict__ stats1, const float2* __restrict__ stats2,
                        float* __restrict__ out, int N) {
    __shared__ float tile[32][33];
    int b = blockIdx.z;
    int n0 = blockIdx.x * 32, o0 = blockIdx.y * 32;
    int tx = threadIdx.x, ty = threadIdx.y;
    const unsigned short* zb = z  + (size_t)b * N * 128;
    const unsigned short* xb = x1 + (size_t)b * N * 128;
    float2 st1 = stats1[b * 128 + o0 + tx];
    float2 st2 = stats2[b * 128 + o0 + tx];
#pragma unroll
    for (int i = 0; i < 32; i += 8) {
        int n = n0 + ty + i;
        float v = 0.f;
        if (n < N) {
            float zv = bf2f(zb[(size_t)n * 128 + o0 + tx]);
            float xv = bf2f(xb[(size_t)n * 128 + o0 + tx]);
            v = (zv - st2.x) * st2.y + (xv - st1.x) * st1.y;
        }
        tile[ty + i][tx] = v;
    }
    __syncthreads();
    float* ob = out + (size_t)b * 128 * N;
#pragma unroll
    for (int i = 0; i < 32; i += 8) {
        int o = o0 + ty + i, n = n0 + tx;
        if (n < N) ob[(size_t)o * N + n] = tile[tx][ty + i];
    }
}

extern "C" void kernel_launch(void* const* d_in, const int* in_sizes, int n_in,
                              void* d_out, int out_size, void* d_ws, size_t ws_size,
                              hipStream_t stream) {
    const float* from_up   = (const float*)d_in[0];  // [2,256,30000]
    const float* from_down = (const float*)d_in[1];  // [2,128,30000]
    const int*   neighbors = (const int*)d_in[2];    // [2,30000,6]
    const float* W_up = (const float*)d_in[3];
    const float* b_up = (const float*)d_in[4];
    const float* W_1  = (const float*)d_in[5];
    const float* b_1  = (const float*)d_in[6];
    const float* W_2  = (const float*)d_in[7];
    const float* b_2  = (const float*)d_in[8];
    float* out = (float*)d_out;

    const int B = 2, N = 30000;
    const int S1 = 56, S3 = 28;        // K-steps: 1792/32, 896/32
    const int NBLK = (N + 127) / 128;  // 235 conv blocks per batch

    char* ws = (char*)d_ws;
    size_t off = 0;
    auto alloc = [&](size_t bytes) {
        char* p = ws + off;
        off += (bytes + 255) & ~(size_t)255;
        return p;
    };
    unsigned short* upT   = (unsigned short*)alloc((size_t)B * N * 256 * 2);
    unsigned short* catT  = (unsigned short*)alloc((size_t)B * N * 256 * 2);
    unsigned short* x1    = (unsigned short*)alloc((size_t)B * N * 128 * 2);
    unsigned short* Wp0   = (unsigned short*)alloc((size_t)S1 * 512 * 8 * 2);
    unsigned short* Wp1   = (unsigned short*)alloc((size_t)S1 * 512 * 8 * 2);
    unsigned short* Wp2b  = (unsigned short*)alloc((size_t)B * S3 * 512 * 8 * 2);
    float*  b2fold = (float*)alloc((size_t)B * 128 * 4);
    float2* part   = (float2*)alloc((size_t)B * NBLK * 128 * 8);
    float2* stats1 = (float2*)alloc((size_t)B * 128 * 8);
    float2* stats2 = (float2*)alloc((size_t)B * 128 * 8);
    unsigned short* zbuf = upT;  // reuse (upT dead after conv1)

    // prepack static weights
    prepack_w<<<(S1 * 512 + 255) / 256, 256, 0, stream>>>(W_up, Wp0, 256, S1);
    prepack_w<<<(S1 * 512 + 255) / 256, 256, 0, stream>>>(W_1,  Wp1, 256, S1);

    // transpose inputs to [B][N][C] bf16
    dim3 tb(32, 8);
    transpose_cast<<<dim3((N + 31) / 32, 256 / 32, B), tb, 0, stream>>>(from_up, upT, 256, N, 256, 0);
    transpose_cast<<<dim3((N + 31) / 32, 128 / 32, B), tb, 0, stream>>>(from_down, catT, 128, N, 256, 128);

    dim3 cgrid(NBLK, B);
    // conv1: upT (Cin=256) -> catT[:, 0:128]
    conv_gemm<256, 256, false><<<cgrid, 256, 0, stream>>>(
        upT, neighbors, Wp0, 0, b_up, 0, catT, nullptr, N, 0);
    // conv2: catT (Cin=256) -> x1, fused stats partials
    conv_gemm<256, 128, true><<<cgrid, 256, 0, stream>>>(
        catT, neighbors, Wp1, 0, b_1, 0, x1, part, N, 0);
    stats_final<<<B, 1024, 0, stream>>>((const float2*)part, stats1, N, NBLK);

    // fold norm1 into conv3's weights/bias (per batch)
    prepack_w_scaled<<<(B * S3 * 512 + 255) / 256, 256, 0, stream>>>(W_2, stats1, Wp2b, 128, S3);
    fold_bias2<<<B, 128, 0, stream>>>(W_2, b_2, stats1, b2fold);

    // conv3: x1 (Cin=128, scaled weights) -> zbuf, fused stats partials
    conv_gemm<128, 128, true><<<cgrid, 256, 0, stream>>>(
        x1, neighbors, Wp2b, (size_t)S3 * 8192, b2fold, 128, zbuf, part, N, 0);
    stats_final<<<B, 1024, 0, stream>>>((const float2*)part, stats2, N, NBLK);

    // final: normalize z, add recomputed x1n, transpose to [B][128][N] fp32
    final_k<<<dim3((N + 31) / 32, 4, B), tb, 0, stream>>>(zbuf, x1, stats1, stats2, out, N);
}

// Round 9
// 182.599 us; speedup vs baseline: 1.6217x; 1.0317x over previous
//
#include <hip/hip_runtime.h>

typedef __attribute__((ext_vector_type(8))) short short8;
typedef __attribute__((ext_vector_type(4))) float f32x4;

static __device__ __forceinline__ float bf2f(unsigned short u) {
    unsigned int x = ((unsigned int)u) << 16;
    union { unsigned int i; float f; } c; c.i = x; return c.f;
}
static __device__ __forceinline__ unsigned short f2bf(float f) {
    union { float f; unsigned int i; } c; c.f = f;
    unsigned int x = c.i;
    unsigned int r = (x + 0x7FFFu + ((x >> 16) & 1u)) >> 16;
    return (unsigned short)r;
}
static __device__ __forceinline__ void glds16(const char* g, char* l) {
    __builtin_amdgcn_global_load_lds(
        (const __attribute__((address_space(1))) unsigned int*)g,
        (__attribute__((address_space(3))) unsigned int*)l, 16, 0, 0);
}

// ---------------- prepack W [Cout=128][Cin][7] fp32 -> fragment-linear bf16 ----------------
__global__ void prepack_w(const float* __restrict__ W, unsigned short* __restrict__ Wp,
                          int Cin, int S) {
    int tid = blockIdx.x * blockDim.x + threadIdx.x;
    if (tid >= S * 512) return;
    int lane = tid & 63;
    int f = (tid >> 6) & 7;
    int s = tid >> 9;
    int o = f * 16 + (lane & 15);
    int kbase = s * 32 + 8 * (lane >> 4);
    unsigned short* dst = Wp + (size_t)tid * 8;
#pragma unroll
    for (int j = 0; j < 8; ++j) {
        int kk = kbase + j;
        int t = kk / Cin;
        int c = kk - t * Cin;
        dst[j] = f2bf(W[((size_t)o * Cin + c) * 7 + t]);
    }
}

__global__ void prepack_w_scaled(const float* __restrict__ W, const float2* __restrict__ stats,
                                 unsigned short* __restrict__ Wp, int Cin, int S) {
    int tid = blockIdx.x * blockDim.x + threadIdx.x;
    if (tid >= 2 * S * 512) return;
    int b = tid / (S * 512);
    int rem = tid - b * S * 512;
    int lane = rem & 63;
    int f = (rem >> 6) & 7;
    int s = rem >> 9;
    int o = f * 16 + (lane & 15);
    int kbase = s * 32 + 8 * (lane >> 4);
    unsigned short* dst = Wp + (size_t)tid * 8;
#pragma unroll
    for (int j = 0; j < 8; ++j) {
        int kk = kbase + j;
        int t = kk / Cin;
        int c = kk - t * Cin;
        float scale = stats[b * 128 + c].y;
        dst[j] = f2bf(W[((size_t)o * Cin + c) * 7 + t] * scale);
    }
}

__global__ void fold_bias2(const float* __restrict__ W2, const float* __restrict__ b2,
                           const float2* __restrict__ stats, float* __restrict__ b2out) {
    int b = blockIdx.x, o = threadIdx.x;
    float sum = 0.f;
    for (int c = 0; c < 128; ++c) {
        float2 st = stats[b * 128 + c];
        float sm = st.x * st.y;
        float ws = 0.f;
#pragma unroll
        for (int t = 0; t < 7; ++t) ws += W2[((size_t)o * 128 + c) * 7 + t];
        sum += ws * sm;
    }
    b2out[b * 128 + o] = b2[o] - sum;
}

// ---------------- transpose fp32 [B][C][N] -> bf16 [B][N][ldo] at column offset ----------------
__global__ void transpose_cast(const float* __restrict__ in, unsigned short* __restrict__ out,
                               int C, int N, int ldo, int coff) {
    __shared__ float tile[32][33];
    int b = blockIdx.z;
    int n0 = blockIdx.x * 32;
    int c0 = blockIdx.y * 32;
    const float* inb = in + (size_t)b * C * N;
    unsigned short* outb = out + (size_t)b * N * ldo;
    int tx = threadIdx.x, ty = threadIdx.y;
#pragma unroll
    for (int i = 0; i < 32; i += 8) {
        int c = c0 + ty + i, n = n0 + tx;
        float v = 0.f;
        if (n < N) v = inb[(size_t)c * N + n];
        tile[ty + i][tx] = v;
    }
    __syncthreads();
#pragma unroll
    for (int i = 0; i < 32; i += 8) {
        int n = n0 + ty + i, c = c0 + tx;
        if (n < N) outb[(size_t)n * ldo + coff + c] = f2bf(tile[tx][ty + i]);
    }
}

// ---------------- GEMM-ified gather-conv: 256 pts x 128 couts, 8 waves ----------------
// Wave = 64 pts (pg=wid&3) x 64 couts (h=wid>>2). K-loop BK=32: A = 256 rows x 64B
// (16KB), W = 8KB. 4-buf rotation, depth-3 prefetch, stage AFTER barrier (race-free:
// writer (s+3)&3's last reader was step s-1, complete pre-barrier), counted vmcnt(6).
// Uniform 3 glds/wave/k-step: 2 A-chunks + 1 W-chunk.
template<int CS, int LD, bool STATS>
__global__ __launch_bounds__(512, 2) void conv_gemm(
    const unsigned short* __restrict__ src,
    const int* __restrict__ nbrs,
    const unsigned short* __restrict__ Wp, size_t w_bstride_bytes,
    const float* __restrict__ bias, int bias_bstride,
    unsigned short* __restrict__ dst,
    float2* __restrict__ part,
    int N, int coff)
{
    constexpr int ROWB = CS * 2;
    constexpr int SPT  = CS / 32;   // k-steps per tap
    constexpr int S    = SPT * 7;   // total k-steps
    constexpr int BUFB = 24576;     // 16KB A + 8KB W per buffer

    const int tid  = threadIdx.x;
    const int lane = tid & 63;
    const int wid  = tid >> 6;      // 0..7
    const int pg   = wid & 3;       // point quarter (compute)
    const int h    = wid >> 2;      // cout half (compute)
    const int l15  = lane & 15;
    const int ks   = lane >> 4;
    const int b    = blockIdx.y;
    const int pblk = blockIdx.x * 256;

    const char* srcb = (const char*)src + (size_t)b * N * ROWB;
    const char* wbc  = (const char*)Wp + (size_t)b * w_bstride_bytes;

    __shared__ char smem[4 * BUFB];   // 96KB

    // --- prologue: wave wid stages rows [wid*32, wid*32+32); lane<32 owns one point ---
    int roffA[14];
    {
        int p = pblk + wid * 32 + (lane & 31);
        int pe = p < N ? p : N - 1;
        int offs[7];
        offs[0] = pe * ROWB;
        const int* nb = nbrs + ((size_t)b * N + pe) * 6;
#pragma unroll
        for (int t = 1; t < 7; ++t) offs[t] = nb[t - 1] * ROWB;
#pragma unroll
        for (int t = 0; t < 7; ++t)
#pragma unroll
            for (int i = 0; i < 2; ++i)
                roffA[t * 2 + i] = __shfl(offs[t], i * 16 + (lane >> 2));
    }
    asm volatile("s_waitcnt vmcnt(0)" ::: "memory");
    __builtin_amdgcn_sched_barrier(0);

    // source-side XOR swizzle: granule (lane&3) holds global granule (lane&3)^f(cr),
    // cr = lane>>2 (chunk row), f(cr) = (cr&3)^((cr>>2)&3)
    const int asw = (((lane & 3) ^ ((lane >> 2) & 3) ^ ((lane >> 4) & 3)) << 4);

    auto stage_all = [&](int t, int kk, int s, int buf) {
        char* base = smem + buf * BUFB;
#pragma unroll
        for (int i = 0; i < 2; ++i)
            glds16(srcb + roffA[t * 2 + i] + kk * 64 + asw,
                   base + (wid * 2 + i) * 1024);
        glds16(wbc + (size_t)s * 8192 + wid * 1024 + lane * 16,
               base + 16384 + wid * 1024);
    };

    f32x4 acc[4][4];
#pragma unroll
    for (int rg = 0; rg < 4; ++rg)
#pragma unroll
        for (int fi = 0; fi < 4; ++fi) acc[rg][fi] = (f32x4){0.f, 0.f, 0.f, 0.f};

    stage_all(0, 0, 0, 0);
    stage_all(1 / SPT, 1 % SPT, 1, 1);
    stage_all(2 / SPT, 2 % SPT, 2, 2);

    const int arsw = (((l15 & 3) ^ ((l15 >> 2) & 3)) << 4);  // f(row)<<4 on read side

#pragma unroll
    for (int t = 0; t < 7; ++t) {
#pragma unroll
        for (int kk = 0; kk < SPT; ++kk) {
            const int s = t * SPT + kk;
            if (s + 2 < S)      { asm volatile("s_waitcnt vmcnt(6)" ::: "memory"); }
            else if (s + 1 < S) { asm volatile("s_waitcnt vmcnt(3)" ::: "memory"); }
            else                { asm volatile("s_waitcnt vmcnt(0)" ::: "memory"); }
            __builtin_amdgcn_sched_barrier(0);
            __builtin_amdgcn_s_barrier();
            __builtin_amdgcn_sched_barrier(0);
            if (s + 3 < S) {
                const int s3 = s + 3;
                stage_all(s3 / SPT, s3 % SPT, s3, s3 & 3);
            }

            const char* Ab = smem + (s & 3) * BUFB;
            const char* Wb = Ab + 16384;
            short8 a[4], w[4];
#pragma unroll
            for (int rg = 0; rg < 4; ++rg)
                a[rg] = *(const short8*)(Ab + (pg * 64 + rg * 16 + l15) * 64 +
                                         ((ks << 4) ^ arsw));
#pragma unroll
            for (int fi = 0; fi < 4; ++fi)
                w[fi] = *(const short8*)(Wb + (h * 4 + fi) * 1024 + lane * 16);
            __builtin_amdgcn_s_setprio(1);
#pragma unroll
            for (int rg = 0; rg < 4; ++rg)
#pragma unroll
                for (int fi = 0; fi < 4; ++fi)
                    acc[rg][fi] = __builtin_amdgcn_mfma_f32_16x16x32_bf16(
                        a[rg], w[fi], acc[rg][fi], 0, 0, 0);
            __builtin_amdgcn_s_setprio(0);
        }
    }

    // --- epilogue: bias, store bf16, fused stats ---
    const float* biasb = bias + (size_t)b * bias_bstride + h * 64;
    float bias_v[4];
#pragma unroll
    for (int fi = 0; fi < 4; ++fi) bias_v[fi] = biasb[fi * 16 + l15];

    unsigned short* dstb = dst + (size_t)b * N * LD + coff + h * 64;
#pragma unroll
    for (int rg = 0; rg < 4; ++rg) {
#pragma unroll
        for (int r = 0; r < 4; ++r) {
            int p = pblk + pg * 64 + rg * 16 + ks * 4 + r;
            if (p < N) {
#pragma unroll
                for (int fi = 0; fi < 4; ++fi)
                    dstb[(size_t)p * LD + fi * 16 + l15] = f2bf(acc[rg][fi][r] + bias_v[fi]);
            }
        }
    }

    if constexpr (STATS) {
        float s4[4], q4[4];
#pragma unroll
        for (int fi = 0; fi < 4; ++fi) { s4[fi] = 0.f; q4[fi] = 0.f; }
#pragma unroll
        for (int rg = 0; rg < 4; ++rg) {
#pragma unroll
            for (int r = 0; r < 4; ++r) {
                int p = pblk + pg * 64 + rg * 16 + ks * 4 + r;
                if (p < N) {
#pragma unroll
                    for (int fi = 0; fi < 4; ++fi) {
                        float v = acc[rg][fi][r] + bias_v[fi];
                        s4[fi] += v; q4[fi] += v * v;
                    }
                }
            }
        }
#pragma unroll
        for (int fi = 0; fi < 4; ++fi) {
            s4[fi] += __shfl_xor(s4[fi], 16); s4[fi] += __shfl_xor(s4[fi], 32);
            q4[fi] += __shfl_xor(q4[fi], 16); q4[fi] += __shfl_xor(q4[fi], 32);
        }
        __syncthreads();
        float* shs = (float*)smem;       // [8][64]
        float* shq = shs + 512;
        if (lane < 16) {
#pragma unroll
            for (int fi = 0; fi < 4; ++fi) {
                shs[wid * 64 + fi * 16 + l15] = s4[fi];
                shq[wid * 64 + fi * 16 + l15] = q4[fi];
            }
        }
        __syncthreads();
        if (tid < 128) {
            int c = tid;
            int hh = c >> 6, cl = c & 63;   // waves hh*4 + pg, pg=0..3
            float ss = 0.f, qq = 0.f;
#pragma unroll
            for (int p4 = 0; p4 < 4; ++p4) {
                ss += shs[(hh * 4 + p4) * 64 + cl];
                qq += shq[(hh * 4 + p4) * 64 + cl];
            }
            part[((size_t)b * gridDim.x + blockIdx.x) * 128 + c] = make_float2(ss, qq);
        }
    }
}

// ---------------- final reduce of per-block partials -> (mu, rstd) ----------------
__global__ void stats_final(const float2* __restrict__ part, float2* __restrict__ stats,
                            int N, int NB) {
    int b = blockIdx.x;
    int c = threadIdx.x & 127;
    int r = threadIdx.x >> 7;  // 0..7
    float s = 0.f, sq = 0.f;
    const float2* p = part + (size_t)b * NB * 128 + c;
#pragma unroll 4
    for (int i = r; i < NB; i += 8) {
        float2 v = p[(size_t)i * 128];
        s += v.x; sq += v.y;
    }
    __shared__ float shs[8][128], shq[8][128];
    shs[r][c] = s; shq[r][c] = sq;
    __syncthreads();
    if (r == 0) {
#pragma unroll
        for (int i = 1; i < 8; ++i) { s += shs[i][c]; sq += shq[i][c]; }
        float mu = s / N;
        float var = sq / N - mu * mu;
        stats[b * 128 + c] = make_float2(mu, rsqrtf(var + 1e-5f));
    }
}

// ---------------- final: out[b][o][n] = (z-mu2)*rstd2 + (x1-mu1)*rstd1, fp32 transposed ----------------
__global__ void final_k(const unsigned short* __restrict__ z, const unsigned short* __restrict__ x1,
                        const float2* __restrict__ stats1, const float2* __restrict__ stats2,
                        float* __restrict__ out, int N) {
    __shared__ float tile[32][33];
    int b = blockIdx.z;
    int n0 = blockIdx.x * 32, o0 = blockIdx.y * 32;
    int tx = threadIdx.x, ty = threadIdx.y;
    const unsigned short* zb = z  + (size_t)b * N * 128;
    const unsigned short* xb = x1 + (size_t)b * N * 128;
    float2 st1 = stats1[b * 128 + o0 + tx];
    float2 st2 = stats2[b * 128 + o0 + tx];
#pragma unroll
    for (int i = 0; i < 32; i += 8) {
        int n = n0 + ty + i;
        float v = 0.f;
        if (n < N) {
            float zv = bf2f(zb[(size_t)n * 128 + o0 + tx]);
            float xv = bf2f(xb[(size_t)n * 128 + o0 + tx]);
            v = (zv - st2.x) * st2.y + (xv - st1.x) * st1.y;
        }
        tile[ty + i][tx] = v;
    }
    __syncthreads();
    float* ob = out + (size_t)b * 128 * N;
#pragma unroll
    for (int i = 0; i < 32; i += 8) {
        int o = o0 + ty + i, n = n0 + tx;
        if (n < N) ob[(size_t)o * N + n] = tile[tx][ty + i];
    }
}

extern "C" void kernel_launch(void* const* d_in, const int* in_sizes, int n_in,
                              void* d_out, int out_size, void* d_ws, size_t ws_size,
                              hipStream_t stream) {
    const float* from_up   = (const float*)d_in[0];  // [2,256,30000]
    const float* from_down = (const float*)d_in[1];  // [2,128,30000]
    const int*   neighbors = (const int*)d_in[2];    // [2,30000,6]
    const float* W_up = (const float*)d_in[3];
    const float* b_up = (const float*)d_in[4];
    const float* W_1  = (const float*)d_in[5];
    const float* b_1  = (const float*)d_in[6];
    const float* W_2  = (const float*)d_in[7];
    const float* b_2  = (const float*)d_in[8];
    float* out = (float*)d_out;

    const int B = 2, N = 30000;
    const int S1 = 56, S3 = 28;        // K-steps: 1792/32, 896/32
    const int NBLK = (N + 255) / 256;  // 118 conv blocks per batch

    char* ws = (char*)d_ws;
    size_t off = 0;
    auto alloc = [&](size_t bytes) {
        char* p = ws + off;
        off += (bytes + 255) & ~(size_t)255;
        return p;
    };
    unsigned short* upT   = (unsigned short*)alloc((size_t)B * N * 256 * 2);
    unsigned short* catT  = (unsigned short*)alloc((size_t)B * N * 256 * 2);
    unsigned short* x1    = (unsigned short*)alloc((size_t)B * N * 128 * 2);
    unsigned short* Wp0   = (unsigned short*)alloc((size_t)S1 * 512 * 8 * 2);
    unsigned short* Wp1   = (unsigned short*)alloc((size_t)S1 * 512 * 8 * 2);
    unsigned short* Wp2b  = (unsigned short*)alloc((size_t)B * S3 * 512 * 8 * 2);
    float*  b2fold = (float*)alloc((size_t)B * 128 * 4);
    float2* part   = (float2*)alloc((size_t)B * NBLK * 128 * 8);
    float2* stats1 = (float2*)alloc((size_t)B * 128 * 8);
    float2* stats2 = (float2*)alloc((size_t)B * 128 * 8);
    unsigned short* zbuf = upT;  // reuse (upT dead after conv1)

    // prepack static weights
    prepack_w<<<(S1 * 512 + 255) / 256, 256, 0, stream>>>(W_up, Wp0, 256, S1);
    prepack_w<<<(S1 * 512 + 255) / 256, 256, 0, stream>>>(W_1,  Wp1, 256, S1);

    // transpose inputs to [B][N][C] bf16
    dim3 tb(32, 8);
    transpose_cast<<<dim3((N + 31) / 32, 256 / 32, B), tb, 0, stream>>>(from_up, upT, 256, N, 256, 0);
    transpose_cast<<<dim3((N + 31) / 32, 128 / 32, B), tb, 0, stream>>>(from_down, catT, 128, N, 256, 128);

    dim3 cgrid(NBLK, B);
    // conv1: upT (Cin=256) -> catT[:, 0:128]
    conv_gemm<256, 256, false><<<cgrid, 512, 0, stream>>>(
        upT, neighbors, Wp0, 0, b_up, 0, catT, nullptr, N, 0);
    // conv2: catT (Cin=256) -> x1, fused stats partials
    conv_gemm<256, 128, true><<<cgrid, 512, 0, stream>>>(
        catT, neighbors, Wp1, 0, b_1, 0, x1, part, N, 0);
    stats_final<<<B, 1024, 0, stream>>>((const float2*)part, stats1, N, NBLK);

    // fold norm1 into conv3's weights/bias (per batch)
    prepack_w_scaled<<<(B * S3 * 512 + 255) / 256, 256, 0, stream>>>(W_2, stats1, Wp2b, 128, S3);
    fold_bias2<<<B, 128, 0, stream>>>(W_2, b_2, stats1, b2fold);

    // conv3: x1 (Cin=128, scaled weights) -> zbuf, fused stats partials
    conv_gemm<128, 128, true><<<cgrid, 512, 0, stream>>>(
        x1, neighbors, Wp2b, (size_t)S3 * 8192, b2fold, 128, zbuf, part, N, 0);
    stats_final<<<B, 1024, 0, stream>>>((const float2*)part, stats2, N, NBLK);

    // final: normalize z, add recomputed x1n, transpose to [B][128][N] fp32
    final_k<<<dim3((N + 31) / 32, 4, B), tb, 0, stream>>>(zbuf, x1, stats1, stats2, out, N);
}